// Round 1
// baseline (264.651 us; speedup 1.0000x reference)
//
#include <hip/hip_runtime.h>

#define T_TOTAL 1096
#define WARMUP  365
#define NB      16384
#define T_OUT   (T_TOTAL - WARMUP)   // 731

__global__ __launch_bounds__(64) void tank_kernel(
    const float* __restrict__ pe_in,   // [T, B, 2]
    const float* __restrict__ params,  // [B, 20]
    float* __restrict__ out)           // q [731,B] then et [731,B]
{
    const int b = blockIdx.x * 64 + threadIdx.x;
    const int B = NB;

    float pn[20];
#pragma unroll
    for (int i = 0; i < 20; ++i) pn[i] = params[b * 20 + i];

    // physical params: lo + p*(hi-lo)
    const float kc  = 0.5f  + pn[0]  * 1.0f;
    const float w1  = 1.0f  + pn[1]  * 99.0f;
    const float w2  = 1.0f  + pn[2]  * 99.0f;
    const float k1  = 0.01f + pn[3]  * 0.99f;
    const float k2  = 0.01f + pn[4]  * 0.99f;
    const float a0  = 0.01f + pn[5]  * 0.99f;
    const float b0  = 0.01f + pn[6]  * 0.99f;
    const float c0p = 0.01f + pn[7]  * 0.99f;
    const float h1  = pn[8]  * 90.0f;
    const float h2  = pn[9]  * 100.0f;
    const float a1  = 0.01f + pn[10] * 0.99f;
    const float a2  = 0.01f + pn[11] * 0.99f;
    const float h3  = pn[12] * 100.0f;
    const float b1  = 0.01f + pn[13] * 0.99f;
    const float h4  = pn[14] * 100.0f;
    const float c1p = 0.01f + pn[15] * 0.99f;
    const float d1  = 0.001f+ pn[16] * 0.999f;
    const float e1  = 0.01f + pn[17] * 0.99f;
    const float e2  = 0.01f + pn[18] * 0.99f;
    const float h   = pn[19] * 100.0f;

    const float dt   = 0.5f * (1.0f / 1000.0f);
    const float invw = 1.0f / (w1 + w2);
    const float cxs  = k2 * w1 * invw;     // t2 = max(cxs*xs - cxp*xp, 0)
    const float cxp  = k2 * w2 * invw;
    const float kkA  = 1.0f / (e1 + e2);   // routing constants (loop-invariant)
    const float kkB  = 1.0f / e1;
    const float ccA  = e2 * h * kkA;
    const float dA   = 1.0f / (kkA + dt);
    const float dB   = 1.0f / (kkB + dt);
    const float gA   = kkA - dt;
    const float gB   = kkB - dt;

    // states
    float xf = 0.01f, xp = 0.01f, x2 = 0.01f, xs = 0.01f;
    float x3 = 0.01f, x4 = 0.01f, x5 = 0.01f, qs = 0.01f;

    const float2* __restrict__ pe2 = (const float2*)pe_in;
    float* __restrict__ outq = out;
    float* __restrict__ oute = out + (size_t)T_OUT * B;

    constexpr int U  = 8;             // 1096 = 8 * 137
    constexpr int NG = T_TOTAL / U;   // 137

    float2 cur[U], nxt[U];
#pragma unroll
    for (int i = 0; i < U; ++i) cur[i] = pe2[(size_t)i * B + b];

    for (int g = 0; g < NG; ++g) {
        const int tbase = g * U;
        if (g + 1 < NG) {
#pragma unroll
            for (int i = 0; i < U; ++i)
                nxt[i] = pe2[(size_t)(tbase + U + i) * B + b];
        }
#pragma unroll
        for (int i = 0; i < U; ++i) {
            const int t = tbase + i;
            const float p = fmaxf(cur[i].x, 0.0f);
            const float e = fmaxf(cur[i].y, 0.0f);

            // --- water balance ---
            const float ep = kc * e;
            const float et = fminf(ep, p + xp + xf);
            const float pe = fmaxf(p - et, 0.0f);
            const float x  = xf;
            xf = fmaxf(x - fmaxf(ep - p, 0.0f), 0.0f);
            xp = fmaxf(xp - fmaxf(ep - p - x, 0.0f), 0.0f);
            const float t1 = fmaxf(k1 * fminf(x2, w1 - xp), 0.0f);
            xp = xp + t1;
            x2 = fmaxf(x2 - t1, 0.0f);
            const float t2 = fmaxf(cxs * xs - cxp * xp, 0.0f);
            xp = xp + t2;
            xs = fmaxf(xs - t2, 0.0f);
            const float xppe = xp + pe;
            xf = xf + fmaxf(xppe - w1, 0.0f);
            xp = fminf(w1, xppe);
            const float f1 = a0 * xf;
            const float s1 = (xf - h1) * a1;
            const float s2 = (xf - h2) * a2;
            const float rs = (xf > h2) ? (s1 + s2) : ((xf > h1) ? s1 : 0.0f);
            x2 = x2 + f1;
            xf = fmaxf(xf - (rs + f1), 0.0f);
            const float f2 = b0 * x2;
            const float ri = (x2 > h3) ? (x2 - h3) * b1 : 0.0f;
            x2 = fmaxf(x2 - (f2 + ri), 0.0f);
            x3 = x3 + f2;
            const float f3 = c0p * x3;
            const float rgs = (x3 > h4) ? (x3 - h4) * c1p : 0.0f;
            x3 = fmaxf(x3 - (f3 + rgs), 0.0f);
            x4 = x4 + f3;
            const float rgd = d1 * x4;
            x4 = fmaxf(x4 - rgd, 0.0f);

            // --- routing (both rk1 branches computed in parallel, then select) ---
            const bool  c5   = (x5 >= h);
            const float kk0g = c5 ? gA : gB;    // kk0 - dt
            const float cc0  = c5 ? ccA : 0.0f;
            const float ii   = (rs + ri) + (rgs + rgd);
            const float q1B  = fmaxf(kk0g * dB * qs + (ii + cc0) * dB, 0.0f);
            const float q1A  = fmaxf(kk0g * dA * qs + (ii + cc0 - ccA) * dA, 0.0f);
            const float x5m  = kkB * q1B;       // first-pass x5 (rc1 = 0)
            const bool  cb   = (x5m > h);
            const float q1   = cb ? q1A : q1B;
            x5 = cb ? (kkA * q1A + ccA) : x5m;
            qs = q1;

            if (t >= WARMUP) {
                const int to = t - WARMUP;
                outq[(size_t)to * B + b] = q1;
                oute[(size_t)to * B + b] = et;
            }
        }
#pragma unroll
        for (int i = 0; i < U; ++i) cur[i] = nxt[i];
    }
}

extern "C" void kernel_launch(void* const* d_in, const int* in_sizes, int n_in,
                              void* d_out, int out_size, void* d_ws, size_t ws_size,
                              hipStream_t stream) {
    const float* pe_in  = (const float*)d_in[0];   // [1096, 16384, 2] f32
    const float* params = (const float*)d_in[1];   // [16384, 20] f32
    float* out = (float*)d_out;                    // 2 * 731 * 16384 f32

    tank_kernel<<<NB / 64, 64, 0, stream>>>(pe_in, params, out);
}

// Round 2
// 260.896 us; speedup vs baseline: 1.0144x; 1.0144x over previous
//
#include <hip/hip_runtime.h>

#define T_TOTAL 1096
#define WARMUP  365
#define NB      16384
#define T_OUT   (T_TOTAL - WARMUP)   // 731

__global__ __launch_bounds__(64) void tank_kernel(
    const float* __restrict__ pe_in,   // [T, B, 2]
    const float* __restrict__ params,  // [B, 20]
    float* __restrict__ out)           // q [731,B] then et [731,B]
{
    const int b = blockIdx.x * 64 + threadIdx.x;
    const int B = NB;

    float pn[20];
#pragma unroll
    for (int i = 0; i < 20; ++i) pn[i] = params[b * 20 + i];

    // physical params: lo + p*(hi-lo)
    const float kc  = 0.5f  + pn[0]  * 1.0f;
    const float w1  = 1.0f  + pn[1]  * 99.0f;
    const float w2  = 1.0f  + pn[2]  * 99.0f;
    const float k1  = 0.01f + pn[3]  * 0.99f;
    const float k2  = 0.01f + pn[4]  * 0.99f;
    const float a0  = 0.01f + pn[5]  * 0.99f;
    const float b0  = 0.01f + pn[6]  * 0.99f;
    const float c0p = 0.01f + pn[7]  * 0.99f;
    const float h1  = pn[8]  * 90.0f;
    const float h2  = pn[9]  * 100.0f;
    const float a1  = 0.01f + pn[10] * 0.99f;
    const float a2  = 0.01f + pn[11] * 0.99f;
    const float h3  = pn[12] * 100.0f;
    const float b1  = 0.01f + pn[13] * 0.99f;
    const float h4  = pn[14] * 100.0f;
    const float c1p = 0.01f + pn[15] * 0.99f;
    const float d1  = 0.001f+ pn[16] * 0.999f;
    const float e1  = 0.01f + pn[17] * 0.99f;
    const float e2  = 0.01f + pn[18] * 0.99f;
    const float h   = pn[19] * 100.0f;

    const float dt   = 0.5f * (1.0f / 1000.0f);
    const float invw = 1.0f / (w1 + w2);
    const float cxs  = k2 * w1 * invw;     // t2 = max(cxs*xs - cxp*xp, 0)
    const float cxp  = k2 * w2 * invw;
    const float kkA  = 1.0f / (e1 + e2);   // routing constants (loop-invariant)
    const float kkB  = 1.0f / e1;
    const float ccA  = e2 * h * kkA;
    const float dA   = 1.0f / (kkA + dt);
    const float dB   = 1.0f / (kkB + dt);
    const float gA   = kkA - dt;
    const float gB   = kkB - dt;
    // fused select->fma products (shorten routing critical path)
    const float gAdA = gA * dA, gBdA = gB * dA;
    const float gAdB = gA * dB, gBdB = gB * dB;
    // fused threshold products: (x-h)*a = fma(x, a, -h*a)
    const float nh1a1 = -h1 * a1;
    const float nh2a2 = -h2 * a2;
    const float nh3b1 = -h3 * b1;
    const float nh4c1 = -h4 * c1p;

    // states
    float xf = 0.01f, xp = 0.01f, x2 = 0.01f, xs = 0.01f;
    float x3 = 0.01f, x4 = 0.01f, x5 = 0.01f, qs = 0.01f;

    const float2* __restrict__ pin = (const float2*)pe_in + b;  // stride B
    float* __restrict__ outq = out + b;
    float* __restrict__ oute = out + (size_t)T_OUT * B + b;

    constexpr int U  = 8;             // 1096 = 8 * 137
    constexpr int NG = T_TOTAL / U;   // 137

    // Rotating prefetch buffer: buf[i] holds the input for step (g*U + i).
    // Each slot is consumed then IMMEDIATELY overwritten with group g+1's
    // value, so the load is live across the loop back-edge (compiler cannot
    // sink it to the use site) and has ~8 steps of compute to cover latency.
    float2 buf[U];
#pragma unroll
    for (int i = 0; i < U; ++i) buf[i] = pin[(size_t)i * B];

    for (int g = 0; g < NG; ++g) {
        const int tbase = g * U;
        // next-group base; last group harmlessly reloads group 0 (in bounds)
        const size_t nbase = (g + 1 < NG) ? (size_t)(tbase + U) : 0;
#pragma unroll
        for (int i = 0; i < U; ++i) {
            const int t = tbase + i;
            const float p = fmaxf(buf[i].x, 0.0f);
            const float e = fmaxf(buf[i].y, 0.0f);
            buf[i] = pin[(nbase + i) * B];   // prefetch for group g+1

            // --- water balance ---
            const float ep = kc * e;
            const float et = fminf(ep, p + xp + xf);
            const float pe = fmaxf(p - et, 0.0f);
            const float x  = xf;
            xf = fmaxf(x - fmaxf(ep - p, 0.0f), 0.0f);
            xp = fmaxf(xp - fmaxf(ep - p - x, 0.0f), 0.0f);
            const float t1 = fmaxf(k1 * fminf(x2, w1 - xp), 0.0f);
            xp = xp + t1;
            x2 = fmaxf(x2 - t1, 0.0f);
            const float t2 = fmaxf(fmaf(cxs, xs, -(cxp * xp)), 0.0f);
            xp = xp + t2;
            xs = fmaxf(xs - t2, 0.0f);
            const float xppe = xp + pe;
            xf = xf + fmaxf(xppe - w1, 0.0f);
            xp = fminf(w1, xppe);
            const float f1 = a0 * xf;
            const float s1 = fmaf(xf, a1, nh1a1);      // (xf-h1)*a1
            const float s2 = fmaf(xf, a2, nh2a2);      // (xf-h2)*a2
            const float rs = (xf > h2) ? (s1 + s2) : ((xf > h1) ? s1 : 0.0f);
            x2 = x2 + f1;
            xf = fmaxf(xf - (rs + f1), 0.0f);
            const float f2 = b0 * x2;
            const float ri = (x2 > h3) ? fmaf(x2, b1, nh3b1) : 0.0f;
            x2 = fmaxf(x2 - (f2 + ri), 0.0f);
            x3 = x3 + f2;
            const float f3 = c0p * x3;
            const float rgs = (x3 > h4) ? fmaf(x3, c1p, nh4c1) : 0.0f;
            x3 = fmaxf(x3 - (f3 + rgs), 0.0f);
            x4 = x4 + f3;
            const float rgd = d1 * x4;
            x4 = fmaxf(x4 - rgd, 0.0f);

            // --- routing (both rk1 branches in parallel, then select) ---
            const bool  c5  = (x5 >= h);
            const float cc0 = c5 ? ccA : 0.0f;
            const float ii  = (rs + ri) + (rgs + rgd);
            const float q1B = fmaxf(fmaf(c5 ? gAdB : gBdB, qs, (ii + cc0) * dB), 0.0f);
            const float q1A = fmaxf(fmaf(c5 ? gAdA : gBdA, qs, (ii + cc0 - ccA) * dA), 0.0f);
            const float x5m = kkB * q1B;       // first-pass x5 (rc1 = 0)
            const bool  cb  = (x5m > h);
            const float q1  = cb ? q1A : q1B;
            x5 = cb ? fmaf(kkA, q1A, ccA) : x5m;
            qs = q1;

            if (t >= WARMUP) {
                const size_t to = (size_t)(t - WARMUP) * B;
                outq[to] = q1;
                oute[to] = et;
            }
        }
    }
}

extern "C" void kernel_launch(void* const* d_in, const int* in_sizes, int n_in,
                              void* d_out, int out_size, void* d_ws, size_t ws_size,
                              hipStream_t stream) {
    const float* pe_in  = (const float*)d_in[0];   // [1096, 16384, 2] f32
    const float* params = (const float*)d_in[1];   // [16384, 20] f32
    float* out = (float*)d_out;                    // 2 * 731 * 16384 f32

    tank_kernel<<<NB / 64, 64, 0, stream>>>(pe_in, params, out);
}